// Round 6
// baseline (24.841 us; speedup 1.0000x reference)
//
#include <hip/hip_runtime.h>

// out[r,s,j,a] = sum_b skts[r,j,a,b] * pts_h[r,s,b],  a in 0..2
// pts:  [R=4096, S=96, 3]   f32
// skts: [R=4096, J=24, 4,4] f32
// out:  [R, S, J, 3]        f32  (113 MB -> store-bound)
//
// v6: minimal-sync. RPB=1, single barrier (stage -> compute/store), matrix
// rows in 12 registers (3x ds_read_b128 once), pts[s][4] LDS broadcast reads,
// non-temporal stores. No mid-kernel vmcnt(0) store drain anywhere.

constexpr int S_DIM = 96;
constexpr int J_DIM = 24;
constexpr int BLOCK = 384;                  // 6 waves; 384 % 24 == 0
constexpr int SKT_STR   = 20;               // 80B row stride: quad = 5j mod 8 sweeps all bank-quads
constexpr int SKT_WORDS = J_DIM * SKT_STR;  // 480
constexpr int PTS_WORDS = S_DIM * 4;        // [s][4], w = 1.0 pad
constexpr int ITERS = S_DIM * J_DIM / BLOCK;        // 6
constexpr int RAY_FLOATS = S_DIM * J_DIM * 3;       // 6912

typedef float f32x3 __attribute__((ext_vector_type(3)));

__global__ __launch_bounds__(BLOCK) void w2l_kernel(
    const float* __restrict__ pts,
    const float* __restrict__ skts,
    float* __restrict__ out) {

    const int tid = threadIdx.x;
    const int r   = blockIdx.x;

    __shared__ __align__(16) float s_skt[SKT_WORDS];
    __shared__ __align__(16) float s_pts[PTS_WORDS];

    // ---- stage: tids 0..95 load skt float4s (+ seed w=1 pads); tids 96..383 load the 288 pts scalars ----
    if (tid < 96) {
        float4 v = reinterpret_cast<const float4*>(skts + (size_t)r * (J_DIM * 16))[tid];
        int jj = tid >> 2, a = tid & 3;                       // tid = j*4 + a
        *reinterpret_cast<float4*>(&s_skt[jj * SKT_STR + a * 4]) = v;
        s_pts[tid * 4 + 3] = 1.0f;                            // tid doubles as s for the pad
    } else {
        int q = tid - 96;                                     // 0..287, coalesced
        float v = pts[(size_t)r * (S_DIM * 3) + q];
        int s = q / 3, c = q - 3 * s;
        s_pts[s * 4 + c] = v;
    }
    __syncthreads();

    const int s0 = tid / J_DIM;             // 0..15
    const int j  = tid - s0 * J_DIM;        // invariant per thread

    const float4 B0 = *reinterpret_cast<const float4*>(&s_skt[j * SKT_STR + 0]);
    const float4 B1 = *reinterpret_cast<const float4*>(&s_skt[j * SKT_STR + 4]);
    const float4 B2 = *reinterpret_cast<const float4*>(&s_skt[j * SKT_STR + 8]);

    float* __restrict__ out_r = out + (size_t)r * RAY_FLOATS;

    #pragma unroll
    for (int it = 0; it < ITERS; ++it) {
        const int s = s0 + it * 16;
        const float4 P = *reinterpret_cast<const float4*>(&s_pts[s * 4]);

        f32x3 o;
        o.x = fmaf(B0.x, P.x, fmaf(B0.y, P.y, fmaf(B0.z, P.z, B0.w)));
        o.y = fmaf(B1.x, P.x, fmaf(B1.y, P.y, fmaf(B1.z, P.z, B1.w)));
        o.z = fmaf(B2.x, P.x, fmaf(B2.y, P.y, fmaf(B2.z, P.z, B2.w)));

        const int p = tid + it * BLOCK;     // consecutive lanes -> contiguous 12B chunks
        __builtin_nontemporal_store(o, reinterpret_cast<f32x3*>(out_r + (size_t)p * 3));
    }
}

extern "C" void kernel_launch(void* const* d_in, const int* in_sizes, int n_in,
                              void* d_out, int out_size, void* d_ws, size_t ws_size,
                              hipStream_t stream) {
    const float* pts  = (const float*)d_in[0];
    const float* skts = (const float*)d_in[1];
    float* out = (float*)d_out;

    const int R = in_sizes[0] / (S_DIM * 3);   // 4096
    w2l_kernel<<<R, BLOCK, 0, stream>>>(pts, skts, out);
}